// Round 1
// baseline (250.677 us; speedup 1.0000x reference)
//
#include <hip/hip_runtime.h>

#define BB 8
#define TT_DIM 128
#define SS 512
#define DD 512
// C == D == 512

// ---------------------------------------------------------------------------
// Generic row-tiled GEMM: Y[n,d] = sum_k X[n,k]*W[k,d] + bias[d]
// K = DO = 512 hardcoded. grid = (N/RN, 2), block = 256 (each thread one d).
// ---------------------------------------------------------------------------
template<int RN>
__global__ __launch_bounds__(256) void map_gemm(
    const float* __restrict__ X, const float* __restrict__ W,
    const float* __restrict__ bias, float* __restrict__ Y) {
  int d = blockIdx.y * 256 + threadIdx.x;
  int n0 = blockIdx.x * RN;
  __shared__ float xs[RN][512];
  for (int idx = threadIdx.x; idx < RN * 512; idx += 256) {
    xs[idx >> 9][idx & 511] = X[(n0 + (idx >> 9)) * 512 + (idx & 511)];
  }
  __syncthreads();
  float bv = bias[d];
  float acc[RN];
#pragma unroll
  for (int r = 0; r < RN; ++r) acc[r] = bv;
  for (int k = 0; k < 512; ++k) {
    float w = W[k * 512 + d];
#pragma unroll
    for (int r = 0; r < RN; ++r) acc[r] = fmaf(xs[r][k], w, acc[r]);
  }
#pragma unroll
  for (int r = 0; r < RN; ++r) Y[(n0 + r) * 512 + d] = acc[r];
}

// ---------------------------------------------------------------------------
// logits[b,t,s] = sum_d tanh(mo[b,t,d] + ma[b,s,d]) * q[d] + qb
// grid = (B*T/4, 8), block = 256 (4 waves). Wave handles 16 s-values.
// Lanes over d (coalesced ma reads); mo/q hoisted to registers; 4 t-rows per
// block so each ma element is reused 4x.
// ---------------------------------------------------------------------------
#define LT 4
__global__ __launch_bounds__(256) void logits_kernel(
    const float* __restrict__ mo, const float* __restrict__ ma,
    const float* __restrict__ qw, const float* __restrict__ qb,
    float* __restrict__ logits) {
  int bt0 = blockIdx.x * LT;         // 4 consecutive (b,t); same b (T%4==0)
  int b = bt0 / TT_DIM;
  int lane = threadIdx.x & 63;
  int wave = threadIdx.x >> 6;
  float moR[LT][8], qR[8];
#pragma unroll
  for (int i = 0; i < 8; ++i) {
    int dd = lane + 64 * i;
    qR[i] = qw[dd];
#pragma unroll
    for (int t = 0; t < LT; ++t) moR[t][i] = mo[(bt0 + t) * DD + dd];
  }
  const float* maB = ma + (size_t)b * SS * DD;
  float qbv = qb[0];
  int s0 = blockIdx.y * 64 + wave * 16;
  for (int s = s0; s < s0 + 16; ++s) {
    float acc[LT] = {0.f, 0.f, 0.f, 0.f};
#pragma unroll
    for (int i = 0; i < 8; ++i) {
      float v = maB[s * DD + lane + 64 * i];
#pragma unroll
      for (int t = 0; t < LT; ++t) {
        float x = moR[t][i] + v;
        float e = __builtin_amdgcn_exp2f(x * 2.885390081777927f);  // e^(2x)
        float r = __builtin_amdgcn_rcpf(e + 1.0f);
        acc[t] = fmaf((e - 1.0f) * r, qR[i], acc[t]);              // tanh*q
      }
    }
#pragma unroll
    for (int t = 0; t < LT; ++t) {
      float a = acc[t];
#pragma unroll
      for (int off = 32; off > 0; off >>= 1) a += __shfl_xor(a, off, 64);
      if (lane == 0) logits[(bt0 + t) * SS + s] = a + qbv;
    }
  }
}

// ---------------------------------------------------------------------------
// softmax over rows of 512. grid = B*T, block = 256 (2 elems/thread).
// ---------------------------------------------------------------------------
__global__ __launch_bounds__(256) void softmax_kernel(
    const float* __restrict__ logits, float* __restrict__ attn) {
  int row = blockIdx.x;
  const float* lp = logits + row * SS;
  int lane = threadIdx.x & 63, wave = threadIdx.x >> 6;
  float v0 = lp[threadIdx.x], v1 = lp[threadIdx.x + 256];
  float m = fmaxf(v0, v1);
  __shared__ float redm[4], reds[4];
#pragma unroll
  for (int off = 32; off > 0; off >>= 1) m = fmaxf(m, __shfl_xor(m, off, 64));
  if (lane == 0) redm[wave] = m;
  __syncthreads();
  m = fmaxf(fmaxf(redm[0], redm[1]), fmaxf(redm[2], redm[3]));
  float e0 = __builtin_amdgcn_exp2f((v0 - m) * 1.4426950408889634f);
  float e1 = __builtin_amdgcn_exp2f((v1 - m) * 1.4426950408889634f);
  float ssum = e0 + e1;
#pragma unroll
  for (int off = 32; off > 0; off >>= 1) ssum += __shfl_xor(ssum, off, 64);
  if (lane == 0) reds[wave] = ssum;
  __syncthreads();
  ssum = reds[0] + reds[1] + reds[2] + reds[3];
  float inv = 1.0f / ssum;
  attn[row * SS + threadIdx.x] = e0 * inv;
  attn[row * SS + threadIdx.x + 256] = e1 * inv;
}

// ---------------------------------------------------------------------------
// mix[b,t,c] = sum_s attn[b,t,s] * context[b,s,c]
// grid = (B*T/RN, 2), block = 256.
// ---------------------------------------------------------------------------
template<int RN>
__global__ __launch_bounds__(256) void mix_kernel(
    const float* __restrict__ attn, const float* __restrict__ ctx,
    float* __restrict__ mixo) {
  int bt0 = blockIdx.x * RN;
  int b = bt0 / TT_DIM;
  int c = blockIdx.y * 256 + threadIdx.x;
  __shared__ float as[RN][SS];
  for (int idx = threadIdx.x; idx < RN * SS; idx += 256)
    as[idx >> 9][idx & 511] = attn[(bt0 + (idx >> 9)) * SS + (idx & 511)];
  __syncthreads();
  float acc[RN] = {};
  const float* cb = ctx + (size_t)b * SS * 512;
  for (int s = 0; s < SS; ++s) {
    float cv = cb[s * 512 + c];
#pragma unroll
    for (int r = 0; r < RN; ++r) acc[r] = fmaf(as[r][s], cv, acc[r]);
  }
#pragma unroll
  for (int r = 0; r < RN; ++r) mixo[(bt0 + r) * 512 + c] = acc[r];
}

// ---------------------------------------------------------------------------
// out[b,t,d] = tanh( [mix, output] @ out_w + out_b )   (K = 1024)
// grid = (B*T/RN, 2), block = 256.
// ---------------------------------------------------------------------------
template<int RN>
__global__ __launch_bounds__(256) void final_kernel(
    const float* __restrict__ mixo, const float* __restrict__ output,
    const float* __restrict__ out_w, const float* __restrict__ out_b,
    float* __restrict__ out) {
  int bt0 = blockIdx.x * RN;
  int d = blockIdx.y * 256 + threadIdx.x;
  __shared__ float cs[RN][1024];
  for (int idx = threadIdx.x; idx < RN * 512; idx += 256) {
    int r = idx >> 9, k = idx & 511;
    cs[r][k] = mixo[(bt0 + r) * 512 + k];
    cs[r][512 + k] = output[(bt0 + r) * 512 + k];
  }
  __syncthreads();
  float bv = out_b[d];
  float acc[RN];
#pragma unroll
  for (int r = 0; r < RN; ++r) acc[r] = bv;
  for (int k = 0; k < 1024; ++k) {
    float w = out_w[k * 512 + d];
#pragma unroll
    for (int r = 0; r < RN; ++r) acc[r] = fmaf(cs[r][k], w, acc[r]);
  }
#pragma unroll
  for (int r = 0; r < RN; ++r) {
    float x = acc[r];
    float e = __builtin_amdgcn_exp2f(x * 2.885390081777927f);
    out[(bt0 + r) * 512 + d] = (e - 1.0f) * __builtin_amdgcn_rcpf(e + 1.0f);
  }
}

extern "C" void kernel_launch(void* const* d_in, const int* in_sizes, int n_in,
                              void* d_out, int out_size, void* d_ws, size_t ws_size,
                              hipStream_t stream) {
  const float* output  = (const float*)d_in[0];  // [B,T,D]
  const float* context = (const float*)d_in[1];  // [B,S,C]
  const float* dec_w   = (const float*)d_in[2];  // [D,D]
  const float* dec_b   = (const float*)d_in[3];
  const float* attn_w  = (const float*)d_in[4];  // [C,D]
  const float* attn_b  = (const float*)d_in[5];
  const float* qw      = (const float*)d_in[6];  // [D,1]
  const float* qb      = (const float*)d_in[7];  // [1]
  const float* out_w   = (const float*)d_in[8];  // [1024,512]
  const float* out_b   = (const float*)d_in[9];

  float* out_p  = (float*)d_out;                       // [B,T,D]
  float* attn_p = out_p + (size_t)BB * TT_DIM * DD;    // [B,T,S]

  float* ws    = (float*)d_ws;
  float* mo    = ws;                                   // B*T*D
  float* ma    = mo + (size_t)BB * TT_DIM * DD;        // B*S*D
  float* logit = ma + (size_t)BB * SS * DD;            // B*T*S
  float* mixo  = logit + (size_t)BB * TT_DIM * SS;     // B*T*C

  map_gemm<4><<<dim3(BB * TT_DIM / 4, 2), 256, 0, stream>>>(output, dec_w, dec_b, mo);
  map_gemm<8><<<dim3(BB * SS / 8, 2), 256, 0, stream>>>(context, attn_w, attn_b, ma);
  logits_kernel<<<dim3(BB * TT_DIM / LT, 8), 256, 0, stream>>>(mo, ma, qw, qb, logit);
  softmax_kernel<<<dim3(BB * TT_DIM), 256, 0, stream>>>(logit, attn_p);
  mix_kernel<4><<<dim3(BB * TT_DIM / 4, 2), 256, 0, stream>>>(attn_p, context, mixo);
  final_kernel<4><<<dim3(BB * TT_DIM / 4, 2), 256, 0, stream>>>(mixo, output, out_w, out_b, out_p);
}